// Round 13
// baseline (108.019 us; speedup 1.0000x reference)
//
#include <hip/hip_runtime.h>
#include <math.h>

#define SEQ   4096
#define NOBJ  32
#define IN_F  4
#define HID   64
#define IFEAT 8
#define NPAIR_HALF 496   // 32*31/2 unordered pairs; = 31 tiles * 16
#define NTILE 31

#define TWO_LOG2E 2.8853900817779268f   // 2*log2(e)
#define GP_CLAMP  10.0f                 // E=exp2(g') in [2^-10,2^10]: f16-safe

#if __has_builtin(__builtin_amdgcn_exp2f)
  #define EXP2F(x) __builtin_amdgcn_exp2f(x)
#else
  #define EXP2F(x) exp2f(x)
#endif

typedef _Float16 h2    __attribute__((ext_vector_type(2)));
typedef _Float16 f16x8 __attribute__((ext_vector_type(8)));
typedef short    s16x8 __attribute__((ext_vector_type(8)));
typedef float    f32x4 __attribute__((ext_vector_type(4)));

__device__ __forceinline__ h2 pack2(float a, float b) {
  return __builtin_bit_cast(h2, __builtin_amdgcn_cvt_pkrtz(a, b));
}
__device__ __forceinline__ unsigned pbits(h2 v) { return __builtin_bit_cast(unsigned, v); }

__device__ __forceinline__ f16x8 pack8(float4 a, float4 b) {
  int4 v;
  v.x = (int)pbits(pack2(a.x, a.y));
  v.y = (int)pbits(pack2(a.z, a.w));
  v.z = (int)pbits(pack2(b.x, b.y));
  v.w = (int)pbits(pack2(b.z, b.w));
  return __builtin_bit_cast(f16x8, v);
}

// Packed-f16 reciprocal: bit-trick guess + 2 Newton steps, all full-rate
// v_pk_* ops. Valid for x in [2^-9, 2^11] (su = Ei+Fj, E in [2^-10,2^10]).
__device__ __forceinline__ f16x8 rcp8nr(f16x8 x) {
  const s16x8 magic = (short)0x7799;
  f16x8 r = __builtin_bit_cast(f16x8, (s16x8)(magic - __builtin_bit_cast(s16x8, x)));
  const f16x8 two = (_Float16)2.0f;
  const f16x8 nx = -x;
#if __has_builtin(__builtin_elementwise_fma)
  r = r * __builtin_elementwise_fma(nx, r, two);
  r = r * __builtin_elementwise_fma(nx, r, two);
#else
  r = r * (nx * r + two);
  r = r * (nx * r + two);
#endif
  return r;
}

// f16 dot2 with f32 accumulate (v_dot2_f32_f16)
__device__ __forceinline__ float dot2h(h2 a, h2 b, float c) {
#if __has_builtin(__builtin_amdgcn_fdot2)
  return __builtin_amdgcn_fdot2(a, b, c, false);
#else
  float r = c;
  r = fmaf((float)a.x, (float)b.x, r);
  r = fmaf((float)a.y, (float)b.y, r);
  return r;
#endif
}

// lane^8 within each 16-lane row: DPP row_ror:8 (pure VALU, no LDS pipe)
__device__ __forceinline__ float xor8_f32(float v) {
#if __has_builtin(__builtin_amdgcn_mov_dpp)
  return __builtin_bit_cast(float,
      __builtin_amdgcn_mov_dpp(__builtin_bit_cast(int, v), 0x128, 0xF, 0xF, true));
#else
  return __shfl_xor(v, 8, 16);
#endif
}

// cumulative pair count before row i (i<j ordering): C(i) = i*(63-i)/2
__device__ __forceinline__ int pair_cum(int i) { return (i * (63 - i)) >> 1; }

__device__ __forceinline__ void pair_decode(int q, int& i, int& j) {
  int ii = (int)((63.0f - sqrtf(3969.0f - 8.0f * (float)q)) * 0.5f);
  if (ii > 0 && pair_cum(ii) > q) --ii;   // fp rounding fixups
  if (pair_cum(ii + 1) <= q)     ++ii;
  i = ii;
  j = ii + 1 + (q - pair_cum(ii));
}

// R25: R24 (best, 40.6us) + explicit 2-deep software pipeline in 4a. Model:
// per-wave execution is latency-chain-bound (~14 stall cyc/instr, 4 waves/
// SIMD covers ~60%); compiler used only 56/128 VGPRs and did not hoist tile
// t+1's 8 ds_read_b128 above tile t's ~250-cyc compute chain. Fix: named
// register double-buffers, source order LOAD(t+1) before COMP(t), all 8
// compute bodies unconditional (tile-7 result discarded at store for wv=3;
// pijr[7] fallback keeps loads safe) -> branch-free. ph2/ph3: all B-frag
// reads hoisted above MFMAs. Math identical. Validity: FETCH/WRITE must
// stay ~1.43/1.0 MB (VGPR will rise to ~110-125; watch for spill).
__global__ __launch_bounds__(256, 4) void magnet_fused(
    const float* __restrict__ x,      // [S,32,4]
    const float* __restrict__ L1W,    // [64,4]
    const float* __restrict__ L1b,    // [64]
    const float* __restrict__ L2W,    // [64,64]
    const float* __restrict__ L2b,    // [64]
    const float* __restrict__ I1W,    // [64,64]
    const float* __restrict__ I2W,    // [8,64]
    const float* __restrict__ I3,     // [992,2,4]
    const float* __restrict__ S1W,    // [4,4]
    const float* __restrict__ S1b,    // [4]
    const float* __restrict__ S2W,    // [32,2,2]
    const float* __restrict__ S2b,    // [32,2]
    float* __restrict__ out)          // [S,32,2]
{
  // LDS layout (float units), 8536 floats = 34144 B -> 4 blocks/CU:
  //   [0,1152)     sAtp s0 (ph1 write, ph2 read; never overwritten)
  //   [1152,2304)  sAtp s1
  //   [0,2480)     sv s0: f16[496][10] (4a write, 4b read; sAtp dead)
  //   [2480,3632)  sBtp s0 (ph2 write, ph3 read)
  //   [3632,4784)  sBtp s1
  //   [2480,4960)  sv s1 (4a write; sBtp dead, ph3-end barrier separates)
  //   [4960,6112)  sE s0: f16[32][72] (ph3 write, 4a read)
  //   [6112,7264)  sE s1
  //   [4960,5024)  swpart [64] (init write, combine read pre-ph2; sE later)
  //   [7264,7776)  wB [16][32] uint / part[256] (4b alias)
  //   [8032,8040)  sW [8]
  //   [8040,8536)  ptab32 [496] u32: (i*36)<<16 | (j*36)
  __shared__ __align__(16) float smem[8536];
  unsigned*       sEd0 = (unsigned*)(smem + 4960);  // dword view of f16 E s0
  unsigned*       sEd1 = (unsigned*)(smem + 6112);  // s1
  unsigned*       wB   = (unsigned*)(smem + 7264);  // [16][32]
  float*          part = smem + 7264;               // [256] (aliases wB)
  float*          sW   = smem + 8032;               // [8]
  unsigned*       ptab32 = (unsigned*)(smem + 8040); // [496]
  float*          swpart = smem + 4960;             // [64] (aliases sE s0)

  const int t  = threadIdx.x;
  const int s0 = blockIdx.x * 2;

  // ---- init (no barrier after; consumers are beyond later barriers) ----
  if (t < 64) {                                // sW partials (distributed)
    const int f = t >> 3, seg = t & 7;
    const float4 a = *(const float4*)(I2W + f * HID + seg * 8);
    const float4 b = *(const float4*)(I2W + f * HID + seg * 8 + 4);
    swpart[t] = ((a.x + a.y) + (a.z + a.w)) + ((b.x + b.y) + (b.z + b.w));
  }
  #pragma unroll
  for (int idx = t; idx < 512; idx += 256) {   // wB[n][k2]; rows 8-15 zero
    const int n = idx >> 5, k2 = idx & 31;
    wB[idx] = (n < IFEAT)
      ? pbits(pack2(I2W[n * HID + 2 * k2], I2W[n * HID + 2 * k2 + 1])) : 0u;
  }
  #pragma unroll
  for (int q = t; q < NPAIR_HALF; q += 256) {  // 4a table: premult row offsets
    int i, j; pair_decode(q, i, j);
    ptab32[q] = ((unsigned)(i * 36) << 16) | (unsigned)(j * 36);
  }

  // ---- phase 1: h1 = relu(x @ L1W^T + L1b); x straight from global (L2).
  // pack f16 -> sAtp(ss)[n][k2] ----
  {
    const int n = t & 31, gI = t >> 5, kb = gI * 8;
    const float4 xv0 = *(const float4*)(x + s0 * 128 + n * 4);
    const float4 xv1 = *(const float4*)(x + s0 * 128 + 128 + n * 4);
    float a[2][8];
    #pragma unroll
    for (int r = 0; r < 8; ++r) {
      const int k = kb + r;
      const float4 w = *(const float4*)(L1W + k * 4);   // shared across ss
      const float bias = L1b[k];
      float v0 = bias, v1 = bias;
      v0 = fmaf(xv0.x, w.x, v0); v0 = fmaf(xv0.y, w.y, v0);
      v0 = fmaf(xv0.z, w.z, v0); v0 = fmaf(xv0.w, w.w, v0);
      v1 = fmaf(xv1.x, w.x, v1); v1 = fmaf(xv1.y, w.y, v1);
      v1 = fmaf(xv1.z, w.z, v1); v1 = fmaf(xv1.w, w.w, v1);
      a[0][r] = fmaxf(v0, 0.0f);
      a[1][r] = fmaxf(v1, 0.0f);
    }
    #pragma unroll
    for (int ss = 0; ss < 2; ++ss) {
      unsigned* sAtp = (unsigned*)(smem + ss * 1152);
      int4 pk;
      pk.x = (int)pbits(pack2(a[ss][0], a[ss][1]));
      pk.y = (int)pbits(pack2(a[ss][2], a[ss][3]));
      pk.z = (int)pbits(pack2(a[ss][4], a[ss][5]));
      pk.w = (int)pbits(pack2(a[ss][6], a[ss][7]));
      *(int4*)(sAtp + n * 36 + gI * 4) = pk;
    }
  }
  __syncthreads();

  if (t < IFEAT) {                             // combine sW partials
    float a = 0.0f;
    #pragma unroll
    for (int c = 0; c < 8; ++c) a += swpart[t * 8 + c];
    sW[t] = a;                                 // read in 4a (barriers cover)
  }

  const int lane = t & 63;
  const int wv   = t >> 6;        // wave id
  const int qd   = lane >> 4;     // quad 0..3
  const int ln   = lane & 15;

  // ---- phase 2: h2 = relu(h1 @ L2W^T + L2b) via MFMA. ALL B-frag reads
  // hoisted above the MFMAs; write burst deferred (store-free compute). ----
  {
    const int m = 16 * wv + ln;
    const float* wr = L2W + m * HID;
    const f16x8 A0 = pack8(*(const float4*)(wr + 8 * qd),
                           *(const float4*)(wr + 8 * qd + 4));
    const f16x8 A1 = pack8(*(const float4*)(wr + 32 + 8 * qd),
                           *(const float4*)(wr + 32 + 8 * qd + 4));
    const float4 bias = *(const float4*)(L2b + 16 * wv + 4 * qd);
    f16x8 Bf[2][2][2];
    #pragma unroll
    for (int ss = 0; ss < 2; ++ss) {
      const unsigned* sAtp = (const unsigned*)(smem + ss * 1152);
      #pragma unroll
      for (int nt = 0; nt < 2; ++nt) {
        const int n = nt * 16 + ln;
        Bf[ss][nt][0] = __builtin_bit_cast(f16x8, *(const int4*)(sAtp + n * 36 + 4 * qd));
        Bf[ss][nt][1] = __builtin_bit_cast(f16x8, *(const int4*)(sAtp + n * 36 + 16 + 4 * qd));
      }
    }
    unsigned pk[2][4];
    #pragma unroll
    for (int ss = 0; ss < 2; ++ss) {
      #pragma unroll
      for (int nt = 0; nt < 2; ++nt) {
        f32x4 c; c[0] = bias.x; c[1] = bias.y; c[2] = bias.z; c[3] = bias.w;
        c = __builtin_amdgcn_mfma_f32_16x16x32_f16(A0, Bf[ss][nt][0], c, 0, 0, 0);
        c = __builtin_amdgcn_mfma_f32_16x16x32_f16(A1, Bf[ss][nt][1], c, 0, 0, 0);
        pk[ss][nt * 2]     = pbits(pack2(fmaxf(c[0], 0.f), fmaxf(c[1], 0.f)));
        pk[ss][nt * 2 + 1] = pbits(pack2(fmaxf(c[2], 0.f), fmaxf(c[3], 0.f)));
      }
    }
    #pragma unroll
    for (int ss = 0; ss < 2; ++ss) {           // deferred write burst
      unsigned* sBtp = (unsigned*)(smem + 2480 + ss * 1152);
      #pragma unroll
      for (int nt = 0; nt < 2; ++nt) {
        const int n = nt * 16 + ln;
        sBtp[n * 36 + 8 * wv + 2 * qd]     = pk[ss][nt * 2];
        sBtp[n * 36 + 8 * wv + 2 * qd + 1] = pk[ss][nt * 2 + 1];
      }
    }
  }
  __syncthreads();

  // ---- phase 3: g' = h2 @ (I1W*2log2e)^T via MFMA (scale folded into A);
  // B-frag reads hoisted; E = exp2(g') f16; deferred write burst. ----
  {
    const int m = 16 * wv + ln;
    const float* wr = I1W + m * HID;
    float4 w0 = *(const float4*)(wr + 8 * qd);
    float4 w1 = *(const float4*)(wr + 8 * qd + 4);
    float4 w2 = *(const float4*)(wr + 32 + 8 * qd);
    float4 w3 = *(const float4*)(wr + 32 + 8 * qd + 4);
    const float T = TWO_LOG2E;
    w0.x *= T; w0.y *= T; w0.z *= T; w0.w *= T;
    w1.x *= T; w1.y *= T; w1.z *= T; w1.w *= T;
    w2.x *= T; w2.y *= T; w2.z *= T; w2.w *= T;
    w3.x *= T; w3.y *= T; w3.z *= T; w3.w *= T;
    const f16x8 A0 = pack8(w0, w1);
    const f16x8 A1 = pack8(w2, w3);
    f16x8 Bf[2][2][2];
    #pragma unroll
    for (int ss = 0; ss < 2; ++ss) {
      const unsigned* sBtp = (const unsigned*)(smem + 2480 + ss * 1152);
      #pragma unroll
      for (int nt = 0; nt < 2; ++nt) {
        const int n = nt * 16 + ln;
        Bf[ss][nt][0] = __builtin_bit_cast(f16x8, *(const int4*)(sBtp + n * 36 + 4 * qd));
        Bf[ss][nt][1] = __builtin_bit_cast(f16x8, *(const int4*)(sBtp + n * 36 + 16 + 4 * qd));
      }
    }
    unsigned pk[2][4];
    #pragma unroll
    for (int ss = 0; ss < 2; ++ss) {
      #pragma unroll
      for (int nt = 0; nt < 2; ++nt) {
        f32x4 c; c[0] = 0.f; c[1] = 0.f; c[2] = 0.f; c[3] = 0.f;
        c = __builtin_amdgcn_mfma_f32_16x16x32_f16(A0, Bf[ss][nt][0], c, 0, 0, 0);
        c = __builtin_amdgcn_mfma_f32_16x16x32_f16(A1, Bf[ss][nt][1], c, 0, 0, 0);
        float e[4];
        #pragma unroll
        for (int r = 0; r < 4; ++r) {
          const float gp = fminf(fmaxf(c[r], -GP_CLAMP), GP_CLAMP);  // c is g'
          e[r] = EXP2F(gp);
        }
        pk[ss][nt * 2]     = pbits(pack2(e[0], e[1]));
        pk[ss][nt * 2 + 1] = pbits(pack2(e[2], e[3]));
      }
    }
    #pragma unroll
    for (int ss = 0; ss < 2; ++ss) {           // deferred write burst
      unsigned* sEd = ss ? sEd1 : sEd0;
      #pragma unroll
      for (int nt = 0; nt < 2; ++nt) {
        const int n = nt * 16 + ln;
        sEd[n * 36 + 8 * wv + 2 * qd]     = pk[ss][nt * 2];
        sEd[n * 36 + 8 * wv + 2 * qd + 1] = pk[ss][nt * 2 + 1];
      }
    }
  }
  __syncthreads();   // sBtp reads done + sE settled before 4a overwrites sv

  // ---- phase 4a: explicit 2-deep software pipeline. LOAD(t+1) issues the
  // 8 ds_read_b128 into named register buffers BEFORE COMP(t) consumes its
  // buffer -> every read has a full compute (~250 cyc) of slack. All 8
  // computes branch-free (wv=3 tile-7 discarded at store). ----
  {
    const f16x8 B0 = __builtin_bit_cast(f16x8, *(const int4*)(wB + ln * 32 + 4 * qd));
    const f16x8 B1 = __builtin_bit_cast(f16x8, *(const int4*)(wB + ln * 32 + 16 + 4 * qd));
    const float WfT = sW[ln & 7] * TWO_LOG2E;
    const float n2T = -2.0f * TWO_LOG2E;
    const bool lo = (ln < IFEAT);
    _Float16* svb = lo ? (_Float16*)smem : (_Float16*)(smem + 2480);
    const int col = ln & 7;

    unsigned pijr[8];
    #pragma unroll
    for (int it = 0; it < 7; ++it) pijr[it] = ptab32[(wv + it * 4) * 16 + ln];
    pijr[7] = (wv < 3) ? ptab32[(wv + 28) * 16 + ln] : 0u;

    unsigned svreg[8][2];
    int4 e0_0, e1_0, f0_0, f1_0, g0_0, g1_0, h0_0, h1_0;   // buffer 0
    int4 e0_1, e1_1, f0_1, f1_1, g0_1, g1_1, h0_1, h1_1;   // buffer 1

#define LOADT(IT, B)                                                         \
    {                                                                        \
      const unsigned pij = pijr[IT];                                         \
      const int io = (int)(pij >> 16) + 4 * qd;                              \
      const int jo = (int)(pij & 0xffffu) + 4 * qd;                          \
      e0_##B = *(const int4*)(sEd0 + io);                                    \
      e1_##B = *(const int4*)(sEd0 + io + 16);                               \
      f0_##B = *(const int4*)(sEd0 + jo);                                    \
      f1_##B = *(const int4*)(sEd0 + jo + 16);                               \
      g0_##B = *(const int4*)(sEd1 + io);                                    \
      g1_##B = *(const int4*)(sEd1 + io + 16);                               \
      h0_##B = *(const int4*)(sEd1 + jo);                                    \
      h1_##B = *(const int4*)(sEd1 + jo + 16);                               \
    }

#define COMPT(IT, B)                                                         \
    {                                                                        \
      const f16x8 ei0 = __builtin_bit_cast(f16x8, e0_##B);                   \
      const f16x8 ei1 = __builtin_bit_cast(f16x8, e1_##B);                   \
      const f16x8 fj0 = __builtin_bit_cast(f16x8, f0_##B);                   \
      const f16x8 fj1 = __builtin_bit_cast(f16x8, f1_##B);                   \
      const f16x8 su0 = ei0 + fj0;                                           \
      const f16x8 su1 = ei1 + fj1;                                           \
      const f16x8 A0 = fj0 * rcp8nr(su0);                                    \
      const f16x8 A1 = fj1 * rcp8nr(su1);                                    \
      f32x4 c0; c0[0] = 0.f; c0[1] = 0.f; c0[2] = 0.f; c0[3] = 0.f;          \
      c0 = __builtin_amdgcn_mfma_f32_16x16x32_f16(A0, B0, c0, 0, 0, 0);      \
      c0 = __builtin_amdgcn_mfma_f32_16x16x32_f16(A1, B1, c0, 0, 0, 0);      \
      const f16x8 gi0 = __builtin_bit_cast(f16x8, g0_##B);                   \
      const f16x8 gi1 = __builtin_bit_cast(f16x8, g1_##B);                   \
      const f16x8 hj0 = __builtin_bit_cast(f16x8, h0_##B);                   \
      const f16x8 hj1 = __builtin_bit_cast(f16x8, h1_##B);                   \
      const f16x8 sv0 = gi0 + hj0;                                           \
      const f16x8 sv1 = gi1 + hj1;                                           \
      const f16x8 C0 = hj0 * rcp8nr(sv0);                                    \
      const f16x8 C1 = hj1 * rcp8nr(sv1);                                    \
      f32x4 c1; c1[0] = 0.f; c1[1] = 0.f; c1[2] = 0.f; c1[3] = 0.f;          \
      c1 = __builtin_amdgcn_mfma_f32_16x16x32_f16(C0, B0, c1, 0, 0, 0);      \
      c1 = __builtin_amdgcn_mfma_f32_16x16x32_f16(C1, B1, c1, 0, 0, 0);      \
      float vv[4];                                                           \
      _Pragma("unroll")                                                      \
      for (int r = 0; r < 4; ++r) {                                          \
        const float c1s = xor8_f32(c1[r]);                                   \
        const float mm = lo ? c0[r] : c1s;                                   \
        const float arg = fmaf(n2T, mm, WfT);                                \
        const float e = EXP2F(arg);                                          \
        const float rr = __builtin_amdgcn_rcpf(e + 1.0f);                    \
        vv[r] = fmaf(-2.0f, rr, 1.0f);                                       \
      }                                                                      \
      svreg[IT][0] = pbits(pack2(vv[0], vv[1]));                             \
      svreg[IT][1] = pbits(pack2(vv[2], vv[3]));                             \
    }

    LOADT(0, 0)
    LOADT(1, 1)
    COMPT(0, 0) LOADT(2, 0)
    COMPT(1, 1) LOADT(3, 1)
    COMPT(2, 0) LOADT(4, 0)
    COMPT(3, 1) LOADT(5, 1)
    COMPT(4, 0) LOADT(6, 0)
    COMPT(5, 1) LOADT(7, 1)
    COMPT(6, 0)
    COMPT(7, 1)
#undef LOADT
#undef COMPT

    // deferred write burst (only stores in 4a)
    #pragma unroll
    for (int it = 0; it < 7; ++it) {
      const int base = ((wv + it * 4) * 16 + 4 * qd) * 10 + col;
      const h2 p0 = __builtin_bit_cast(h2, svreg[it][0]);
      const h2 p1 = __builtin_bit_cast(h2, svreg[it][1]);
      svb[base]      = p0.x;
      svb[base + 10] = p0.y;
      svb[base + 20] = p1.x;
      svb[base + 30] = p1.y;
    }
    if (wv < 3) {
      const int base = ((wv + 28) * 16 + 4 * qd) * 10 + col;
      const h2 p0 = __builtin_bit_cast(h2, svreg[7][0]);
      const h2 p1 = __builtin_bit_cast(h2, svreg[7][1]);
      svb[base]      = p0.x;
      svb[base + 10] = p0.y;
      svb[base + 20] = p1.x;
      svb[base + 30] = p1.y;
    }
  }
  __syncthreads();   // sv complete; wB dead -> part may overwrite

  // ---- phase 4b: thread = (ss, i, d, half); gather with INLINE index calc.
  // sv stride 10 f16 -> gather banks (5q+2d)%32, q-uniform. ----
  {
    const int ss = t >> 7, i = (t >> 2) & 31, d = (t >> 1) & 1, half = t & 1;
    const _Float16* sv = ss ? (const _Float16*)(smem + 2480) : (const _Float16*)smem;
    const int msta = half * 16;
    const int Ci = pair_cum(i);
    float sum = 0.0f;
    #pragma unroll
    for (int it = 0; it < 16; ++it) {
      const int m = msta + it;
      if (m < 31) {
        const bool up = (m >= i);                    // j = m+1 > i
        const int q = up ? (Ci + m - i) : (pair_cum(m) + i - m - 1);
        const h2* vp = (const h2*)(sv + q * 10 + d * 4);
        const h2 va = vp[0], vb = vp[1];
        const float4 cf = *(const float4*)(I3 + (i * 31 + m) * 8 + d * 4);
        const h2 ca = pack2(cf.x, cf.y);
        const h2 cb = pack2(cf.z, cf.w);
        float dot = dot2h(va, ca, 0.0f);
        dot = dot2h(vb, cb, dot);
        const float sgn = up ? 1.0f : -1.0f;
        sum = fmaf(sgn, dot, sum);
      }
    }
    part[t] = sum;
  }
  __syncthreads();

  // ---- final: combine partials + self term + store; x from global ----
  if (t < 128) {
    const int ss = t >> 6, i = (t >> 1) & 31, d = t & 1;
    const int pbase = ss * 128 + i * 4 + d * 2;
    float sum = part[pbase] + part[pbase + 1];

    float res = S2b[i * 2 + d] + sum;
    const float4 xv = *(const float4*)(x + (s0 + ss) * 128 + i * 4);
    #pragma unroll
    for (int k = 0; k < 2; ++k) {
      const int f = d * 2 + k;
      float hs = S1b[f];
      hs = fmaf(xv.x, S1W[f * 4 + 0], hs);
      hs = fmaf(xv.y, S1W[f * 4 + 1], hs);
      hs = fmaf(xv.z, S1W[f * 4 + 2], hs);
      hs = fmaf(xv.w, S1W[f * 4 + 3], hs);
      hs = fmaxf(hs, 0.0f);
      res = fmaf(hs, S2W[i * 4 + d * 2 + k], res);
    }
    out[(s0 + ss) * (NOBJ * 2) + i * 2 + d] = res;
  }
}

extern "C" void kernel_launch(void* const* d_in, const int* in_sizes, int n_in,
                              void* d_out, int out_size, void* d_ws, size_t ws_size,
                              hipStream_t stream) {
  const float* x   = (const float*)d_in[0];
  const float* L1W = (const float*)d_in[1];
  const float* L1b = (const float*)d_in[2];
  const float* L2W = (const float*)d_in[3];
  const float* L2b = (const float*)d_in[4];
  const float* I1W = (const float*)d_in[5];
  const float* I2W = (const float*)d_in[6];
  const float* I3  = (const float*)d_in[7];
  const float* S1W = (const float*)d_in[8];
  const float* S1b = (const float*)d_in[9];
  const float* S2W = (const float*)d_in[10];
  const float* S2b = (const float*)d_in[11];
  float* outp = (float*)d_out;

  magnet_fused<<<SEQ / 2, 256, 0, stream>>>(x, L1W, L1b, L2W, L2b, I1W, I2W, I3,
                                            S1W, S1b, S2W, S2b, outp);
}

// Round 14
// 107.087 us; speedup vs baseline: 1.0087x; 1.0087x over previous
//
#include <hip/hip_runtime.h>
#include <math.h>

#define SEQ   4096
#define NOBJ  32
#define IN_F  4
#define HID   64
#define IFEAT 8
#define NPAIR_HALF 496   // 32*31/2 unordered pairs; = 31 tiles * 16
#define NTILE 31

#define TWO_LOG2E 2.8853900817779268f   // 2*log2(e)
#define GP_CLAMP  10.0f                 // E=exp2(g') in [2^-10,2^10]: f16-safe

#if __has_builtin(__builtin_amdgcn_exp2f)
  #define EXP2F(x) __builtin_amdgcn_exp2f(x)
#else
  #define EXP2F(x) exp2f(x)
#endif

typedef _Float16 h2    __attribute__((ext_vector_type(2)));
typedef _Float16 f16x8 __attribute__((ext_vector_type(8)));
typedef short    s16x8 __attribute__((ext_vector_type(8)));
typedef float    f32x4 __attribute__((ext_vector_type(4)));

__device__ __forceinline__ h2 pack2(float a, float b) {
  return __builtin_bit_cast(h2, __builtin_amdgcn_cvt_pkrtz(a, b));
}
__device__ __forceinline__ unsigned pbits(h2 v) { return __builtin_bit_cast(unsigned, v); }

__device__ __forceinline__ f16x8 pack8(float4 a, float4 b) {
  int4 v;
  v.x = (int)pbits(pack2(a.x, a.y));
  v.y = (int)pbits(pack2(a.z, a.w));
  v.z = (int)pbits(pack2(b.x, b.y));
  v.w = (int)pbits(pack2(b.z, b.w));
  return __builtin_bit_cast(f16x8, v);
}

// Packed-f16 reciprocal: bit-trick guess + 2 Newton steps, all full-rate
// v_pk_* ops. Valid for x in [2^-9, 2^11] (su = Ei+Fj, E in [2^-10,2^10]).
__device__ __forceinline__ f16x8 rcp8nr(f16x8 x) {
  const s16x8 magic = (short)0x7799;
  f16x8 r = __builtin_bit_cast(f16x8, (s16x8)(magic - __builtin_bit_cast(s16x8, x)));
  const f16x8 two = (_Float16)2.0f;
  const f16x8 nx = -x;
#if __has_builtin(__builtin_elementwise_fma)
  r = r * __builtin_elementwise_fma(nx, r, two);
  r = r * __builtin_elementwise_fma(nx, r, two);
#else
  r = r * (nx * r + two);
  r = r * (nx * r + two);
#endif
  return r;
}

// f16 dot2 with f32 accumulate (v_dot2_f32_f16)
__device__ __forceinline__ float dot2h(h2 a, h2 b, float c) {
#if __has_builtin(__builtin_amdgcn_fdot2)
  return __builtin_amdgcn_fdot2(a, b, c, false);
#else
  float r = c;
  r = fmaf((float)a.x, (float)b.x, r);
  r = fmaf((float)a.y, (float)b.y, r);
  return r;
#endif
}

// lane^8 within each 16-lane row: DPP row_ror:8 (pure VALU, no LDS pipe)
__device__ __forceinline__ float xor8_f32(float v) {
#if __has_builtin(__builtin_amdgcn_mov_dpp)
  return __builtin_bit_cast(float,
      __builtin_amdgcn_mov_dpp(__builtin_bit_cast(int, v), 0x128, 0xF, 0xF, true));
#else
  return __shfl_xor(v, 8, 16);
#endif
}

// cumulative pair count before row i (i<j ordering): C(i) = i*(63-i)/2
__device__ __forceinline__ int pair_cum(int i) { return (i * (63 - i)) >> 1; }

__device__ __forceinline__ void pair_decode(int q, int& i, int& j) {
  int ii = (int)((63.0f - sqrtf(3969.0f - 8.0f * (float)q)) * 0.5f);
  if (ii > 0 && pair_cum(ii) > q) --ii;   // fp rounding fixups
  if (pair_cum(ii + 1) <= q)     ++ii;
  i = ii;
  j = ii + 1 + (q - pair_cum(ii));
}

// R26 = R24 verbatim (session best: 40.6us dispatch / 107.3us harness).
// R25's explicit 2-deep pipeline REVERTED: it defeated the compiler's
// fine-grained lgkmcnt (busy cycles unchanged, idle +30% — the m141
// order-pinning failure class). Ledger: occupancy (R13/R17/R21), LDS
// layout (R18), VALU work (R15/R19), barriers (R20), 4-seq amortization
// (R22), de-sync (R23), explicit SWP (R25) all null/negative; the wins
// were ss-merged tanh (R14), packed-Newton rcp (R19, enabling), and
// store-free compute loops (R24). Remaining idle is per-wave latency
// chains under barrier lockstep at the toolchain-capped 4 waves/SIMD —
// not reachable from HIP source without inline-asm waitcnt control.
__global__ __launch_bounds__(256, 4) void magnet_fused(
    const float* __restrict__ x,      // [S,32,4]
    const float* __restrict__ L1W,    // [64,4]
    const float* __restrict__ L1b,    // [64]
    const float* __restrict__ L2W,    // [64,64]
    const float* __restrict__ L2b,    // [64]
    const float* __restrict__ I1W,    // [64,64]
    const float* __restrict__ I2W,    // [8,64]
    const float* __restrict__ I3,     // [992,2,4]
    const float* __restrict__ S1W,    // [4,4]
    const float* __restrict__ S1b,    // [4]
    const float* __restrict__ S2W,    // [32,2,2]
    const float* __restrict__ S2b,    // [32,2]
    float* __restrict__ out)          // [S,32,2]
{
  // LDS layout (float units), 8536 floats = 34144 B -> 4 blocks/CU:
  //   [0,1152)     sAtp s0 (ph1 write, ph2 read; never overwritten)
  //   [1152,2304)  sAtp s1
  //   [0,2480)     sv s0: f16[496][10] (4a write, 4b read; sAtp dead)
  //   [2480,3632)  sBtp s0 (ph2 write, ph3 read)
  //   [3632,4784)  sBtp s1
  //   [2480,4960)  sv s1 (4a write; sBtp dead, ph3-end barrier separates)
  //   [4960,6112)  sE s0: f16[32][72] (ph3 write, 4a read)
  //   [6112,7264)  sE s1
  //   [4960,5024)  swpart [64] (init write, combine read pre-ph2; sE later)
  //   [7264,7776)  wB [16][32] uint / part[256] (4b alias)
  //   [8032,8040)  sW [8]
  //   [8040,8536)  ptab32 [496] u32: (i*36)<<16 | (j*36)
  __shared__ __align__(16) float smem[8536];
  unsigned*       sEd0 = (unsigned*)(smem + 4960);  // dword view of f16 E
  unsigned*       wB   = (unsigned*)(smem + 7264);  // [16][32]
  float*          part = smem + 7264;               // [256] (aliases wB)
  float*          sW   = smem + 8032;               // [8]
  unsigned*       ptab32 = (unsigned*)(smem + 8040); // [496]
  float*          swpart = smem + 4960;             // [64] (aliases sE s0)

  const int t  = threadIdx.x;
  const int s0 = blockIdx.x * 2;

  // ---- init (no barrier after; consumers are beyond later barriers) ----
  if (t < 64) {                                // sW partials (distributed)
    const int f = t >> 3, seg = t & 7;
    const float4 a = *(const float4*)(I2W + f * HID + seg * 8);
    const float4 b = *(const float4*)(I2W + f * HID + seg * 8 + 4);
    swpart[t] = ((a.x + a.y) + (a.z + a.w)) + ((b.x + b.y) + (b.z + b.w));
  }
  #pragma unroll
  for (int idx = t; idx < 512; idx += 256) {   // wB[n][k2]; rows 8-15 zero
    const int n = idx >> 5, k2 = idx & 31;
    wB[idx] = (n < IFEAT)
      ? pbits(pack2(I2W[n * HID + 2 * k2], I2W[n * HID + 2 * k2 + 1])) : 0u;
  }
  #pragma unroll
  for (int q = t; q < NPAIR_HALF; q += 256) {  // 4a table: premult row offsets
    int i, j; pair_decode(q, i, j);
    ptab32[q] = ((unsigned)(i * 36) << 16) | (unsigned)(j * 36);
  }

  // ---- phase 1: h1 = relu(x @ L1W^T + L1b); x straight from global (L2).
  // pack f16 -> sAtp(ss)[n][k2] ----
  {
    const int n = t & 31, gI = t >> 5, kb = gI * 8;
    const float4 xv0 = *(const float4*)(x + s0 * 128 + n * 4);
    const float4 xv1 = *(const float4*)(x + s0 * 128 + 128 + n * 4);
    float a[2][8];
    #pragma unroll
    for (int r = 0; r < 8; ++r) {
      const int k = kb + r;
      const float4 w = *(const float4*)(L1W + k * 4);   // shared across ss
      const float bias = L1b[k];
      float v0 = bias, v1 = bias;
      v0 = fmaf(xv0.x, w.x, v0); v0 = fmaf(xv0.y, w.y, v0);
      v0 = fmaf(xv0.z, w.z, v0); v0 = fmaf(xv0.w, w.w, v0);
      v1 = fmaf(xv1.x, w.x, v1); v1 = fmaf(xv1.y, w.y, v1);
      v1 = fmaf(xv1.z, w.z, v1); v1 = fmaf(xv1.w, w.w, v1);
      a[0][r] = fmaxf(v0, 0.0f);
      a[1][r] = fmaxf(v1, 0.0f);
    }
    #pragma unroll
    for (int ss = 0; ss < 2; ++ss) {
      unsigned* sAtp = (unsigned*)(smem + ss * 1152);
      int4 pk;
      pk.x = (int)pbits(pack2(a[ss][0], a[ss][1]));
      pk.y = (int)pbits(pack2(a[ss][2], a[ss][3]));
      pk.z = (int)pbits(pack2(a[ss][4], a[ss][5]));
      pk.w = (int)pbits(pack2(a[ss][6], a[ss][7]));
      *(int4*)(sAtp + n * 36 + gI * 4) = pk;
    }
  }
  __syncthreads();

  if (t < IFEAT) {                             // combine sW partials
    float a = 0.0f;
    #pragma unroll
    for (int c = 0; c < 8; ++c) a += swpart[t * 8 + c];
    sW[t] = a;                                 // read in 4a (barriers cover)
  }

  const int lane = t & 63;
  const int wv   = t >> 6;        // wave id
  const int qd   = lane >> 4;     // quad 0..3
  const int ln   = lane & 15;

  // ---- phase 2: h2 = relu(h1 @ L2W^T + L2b) via MFMA. Reads first, write
  // burst DEFERRED to registers (loop is store-free -> loads pipeline). ----
  {
    const int m = 16 * wv + ln;
    const float* wr = L2W + m * HID;
    const f16x8 A0 = pack8(*(const float4*)(wr + 8 * qd),
                           *(const float4*)(wr + 8 * qd + 4));
    const f16x8 A1 = pack8(*(const float4*)(wr + 32 + 8 * qd),
                           *(const float4*)(wr + 32 + 8 * qd + 4));
    const float4 bias = *(const float4*)(L2b + 16 * wv + 4 * qd);
    unsigned pk[2][4];
    #pragma unroll
    for (int ss = 0; ss < 2; ++ss) {
      const unsigned* sAtp = (const unsigned*)(smem + ss * 1152);
      #pragma unroll
      for (int nt = 0; nt < 2; ++nt) {
        const int n = nt * 16 + ln;
        const f16x8 B0 = __builtin_bit_cast(f16x8, *(const int4*)(sAtp + n * 36 + 4 * qd));
        const f16x8 B1 = __builtin_bit_cast(f16x8, *(const int4*)(sAtp + n * 36 + 16 + 4 * qd));
        f32x4 c; c[0] = bias.x; c[1] = bias.y; c[2] = bias.z; c[3] = bias.w;
        c = __builtin_amdgcn_mfma_f32_16x16x32_f16(A0, B0, c, 0, 0, 0);
        c = __builtin_amdgcn_mfma_f32_16x16x32_f16(A1, B1, c, 0, 0, 0);
        pk[ss][nt * 2]     = pbits(pack2(fmaxf(c[0], 0.f), fmaxf(c[1], 0.f)));
        pk[ss][nt * 2 + 1] = pbits(pack2(fmaxf(c[2], 0.f), fmaxf(c[3], 0.f)));
      }
    }
    #pragma unroll
    for (int ss = 0; ss < 2; ++ss) {           // deferred write burst
      unsigned* sBtp = (unsigned*)(smem + 2480 + ss * 1152);
      #pragma unroll
      for (int nt = 0; nt < 2; ++nt) {
        const int n = nt * 16 + ln;
        sBtp[n * 36 + 8 * wv + 2 * qd]     = pk[ss][nt * 2];
        sBtp[n * 36 + 8 * wv + 2 * qd + 1] = pk[ss][nt * 2 + 1];
      }
    }
  }
  __syncthreads();

  // ---- phase 3: g' = h2 @ (I1W*2log2e)^T via MFMA (scale folded into A);
  // E = exp2(g') f16. Write burst deferred to registers. ----
  {
    const int m = 16 * wv + ln;
    const float* wr = I1W + m * HID;
    float4 w0 = *(const float4*)(wr + 8 * qd);
    float4 w1 = *(const float4*)(wr + 8 * qd + 4);
    float4 w2 = *(const float4*)(wr + 32 + 8 * qd);
    float4 w3 = *(const float4*)(wr + 32 + 8 * qd + 4);
    const float T = TWO_LOG2E;
    w0.x *= T; w0.y *= T; w0.z *= T; w0.w *= T;
    w1.x *= T; w1.y *= T; w1.z *= T; w1.w *= T;
    w2.x *= T; w2.y *= T; w2.z *= T; w2.w *= T;
    w3.x *= T; w3.y *= T; w3.z *= T; w3.w *= T;
    const f16x8 A0 = pack8(w0, w1);
    const f16x8 A1 = pack8(w2, w3);
    unsigned pk[2][4];
    #pragma unroll
    for (int ss = 0; ss < 2; ++ss) {
      const unsigned* sBtp = (const unsigned*)(smem + 2480 + ss * 1152);
      #pragma unroll
      for (int nt = 0; nt < 2; ++nt) {
        const int n = nt * 16 + ln;
        const f16x8 B0 = __builtin_bit_cast(f16x8, *(const int4*)(sBtp + n * 36 + 4 * qd));
        const f16x8 B1 = __builtin_bit_cast(f16x8, *(const int4*)(sBtp + n * 36 + 16 + 4 * qd));
        f32x4 c; c[0] = 0.f; c[1] = 0.f; c[2] = 0.f; c[3] = 0.f;
        c = __builtin_amdgcn_mfma_f32_16x16x32_f16(A0, B0, c, 0, 0, 0);
        c = __builtin_amdgcn_mfma_f32_16x16x32_f16(A1, B1, c, 0, 0, 0);
        float e[4];
        #pragma unroll
        for (int r = 0; r < 4; ++r) {
          const float gp = fminf(fmaxf(c[r], -GP_CLAMP), GP_CLAMP);  // c is g'
          e[r] = EXP2F(gp);
        }
        pk[ss][nt * 2]     = pbits(pack2(e[0], e[1]));
        pk[ss][nt * 2 + 1] = pbits(pack2(e[2], e[3]));
      }
    }
    #pragma unroll
    for (int ss = 0; ss < 2; ++ss) {           // deferred write burst
      unsigned* sEd = sEd0 + ss * 1152;
      #pragma unroll
      for (int nt = 0; nt < 2; ++nt) {
        const int n = nt * 16 + ln;
        sEd[n * 36 + 8 * wv + 2 * qd]     = pk[ss][nt * 2];
        sEd[n * 36 + 8 * wv + 2 * qd + 1] = pk[ss][nt * 2 + 1];
      }
    }
  }
  __syncthreads();   // sBtp reads done + sE settled before 4a overwrites sv

  // ---- phase 4a: pair dots via MFMA, both ss per tile. STORE-FREE main
  // loop (results packed to registers); 7 unguarded iters + guarded tail;
  // single deferred write burst at the end. tanh merged across ss via DPP. ----
  {
    const f16x8 B0 = __builtin_bit_cast(f16x8, *(const int4*)(wB + ln * 32 + 4 * qd));
    const f16x8 B1 = __builtin_bit_cast(f16x8, *(const int4*)(wB + ln * 32 + 16 + 4 * qd));
    const float WfT = sW[ln & 7] * TWO_LOG2E;
    const float n2T = -2.0f * TWO_LOG2E;
    const bool lo = (ln < IFEAT);
    _Float16* svb = lo ? (_Float16*)smem : (_Float16*)(smem + 2480);
    const int col = ln & 7;

    unsigned pijr[8];
    #pragma unroll
    for (int it = 0; it < 7; ++it) pijr[it] = ptab32[(wv + it * 4) * 16 + ln];
    pijr[7] = (wv < 3) ? ptab32[(wv + 28) * 16 + ln] : 0u;

    unsigned svreg[8][2];

#define TILE_BODY(IT)                                                          \
    {                                                                          \
      const unsigned pij = pijr[IT];                                           \
      const int io = (int)(pij >> 16), jo = (int)(pij & 0xffffu);              \
      f32x4 c0, c1;                                                            \
      _Pragma("unroll")                                                        \
      for (int ss = 0; ss < 2; ++ss) {                                         \
        const unsigned* sEd = sEd0 + ss * 1152;                                \
        const f16x8 ei0 = __builtin_bit_cast(f16x8, *(const int4*)(sEd + io + 4 * qd));      \
        const f16x8 ei1 = __builtin_bit_cast(f16x8, *(const int4*)(sEd + io + 16 + 4 * qd)); \
        const f16x8 fj0 = __builtin_bit_cast(f16x8, *(const int4*)(sEd + jo + 4 * qd));      \
        const f16x8 fj1 = __builtin_bit_cast(f16x8, *(const int4*)(sEd + jo + 16 + 4 * qd)); \
        const f16x8 su0 = ei0 + fj0;                                           \
        const f16x8 su1 = ei1 + fj1;                                           \
        const f16x8 A0 = fj0 * rcp8nr(su0);                                    \
        const f16x8 A1 = fj1 * rcp8nr(su1);                                    \
        f32x4 c; c[0] = 0.f; c[1] = 0.f; c[2] = 0.f; c[3] = 0.f;               \
        c = __builtin_amdgcn_mfma_f32_16x16x32_f16(A0, B0, c, 0, 0, 0);        \
        c = __builtin_amdgcn_mfma_f32_16x16x32_f16(A1, B1, c, 0, 0, 0);        \
        if (ss == 0) c0 = c; else c1 = c;                                      \
      }                                                                        \
      float vv[4];                                                             \
      _Pragma("unroll")                                                        \
      for (int r = 0; r < 4; ++r) {                                            \
        const float c1s = xor8_f32(c1[r]);                                     \
        const float m = lo ? c0[r] : c1s;                                      \
        const float arg = fmaf(n2T, m, WfT);                                   \
        const float e = EXP2F(arg);                                            \
        const float rr = __builtin_amdgcn_rcpf(e + 1.0f);                      \
        vv[r] = fmaf(-2.0f, rr, 1.0f);                                         \
      }                                                                        \
      svreg[IT][0] = pbits(pack2(vv[0], vv[1]));                               \
      svreg[IT][1] = pbits(pack2(vv[2], vv[3]));                               \
    }

    #pragma unroll
    for (int it = 0; it < 7; ++it) TILE_BODY(it)
    if (wv < 3) TILE_BODY(7)
#undef TILE_BODY

    // deferred write burst (only stores in 4a)
    #pragma unroll
    for (int it = 0; it < 7; ++it) {
      const int base = ((wv + it * 4) * 16 + 4 * qd) * 10 + col;
      const h2 p0 = __builtin_bit_cast(h2, svreg[it][0]);
      const h2 p1 = __builtin_bit_cast(h2, svreg[it][1]);
      svb[base]      = p0.x;
      svb[base + 10] = p0.y;
      svb[base + 20] = p1.x;
      svb[base + 30] = p1.y;
    }
    if (wv < 3) {
      const int base = ((wv + 28) * 16 + 4 * qd) * 10 + col;
      const h2 p0 = __builtin_bit_cast(h2, svreg[7][0]);
      const h2 p1 = __builtin_bit_cast(h2, svreg[7][1]);
      svb[base]      = p0.x;
      svb[base + 10] = p0.y;
      svb[base + 20] = p1.x;
      svb[base + 30] = p1.y;
    }
  }
  __syncthreads();   // sv complete; wB dead -> part may overwrite

  // ---- phase 4b: thread = (ss, i, d, half); gather with INLINE index calc.
  // sv stride 10 f16 -> gather banks (5q+2d)%32, q-uniform. ----
  {
    const int ss = t >> 7, i = (t >> 2) & 31, d = (t >> 1) & 1, half = t & 1;
    const _Float16* sv = ss ? (const _Float16*)(smem + 2480) : (const _Float16*)smem;
    const int msta = half * 16;
    const int Ci = pair_cum(i);
    float sum = 0.0f;
    #pragma unroll
    for (int it = 0; it < 16; ++it) {
      const int m = msta + it;
      if (m < 31) {
        const bool up = (m >= i);                    // j = m+1 > i
        const int q = up ? (Ci + m - i) : (pair_cum(m) + i - m - 1);
        const h2* vp = (const h2*)(sv + q * 10 + d * 4);
        const h2 va = vp[0], vb = vp[1];
        const float4 cf = *(const float4*)(I3 + (i * 31 + m) * 8 + d * 4);
        const h2 ca = pack2(cf.x, cf.y);
        const h2 cb = pack2(cf.z, cf.w);
        float dot = dot2h(va, ca, 0.0f);
        dot = dot2h(vb, cb, dot);
        const float sgn = up ? 1.0f : -1.0f;
        sum = fmaf(sgn, dot, sum);
      }
    }
    part[t] = sum;
  }
  __syncthreads();

  // ---- final: combine partials + self term + store; x from global ----
  if (t < 128) {
    const int ss = t >> 6, i = (t >> 1) & 31, d = t & 1;
    const int pbase = ss * 128 + i * 4 + d * 2;
    float sum = part[pbase] + part[pbase + 1];

    float res = S2b[i * 2 + d] + sum;
    const float4 xv = *(const float4*)(x + (s0 + ss) * 128 + i * 4);
    #pragma unroll
    for (int k = 0; k < 2; ++k) {
      const int f = d * 2 + k;
      float hs = S1b[f];
      hs = fmaf(xv.x, S1W[f * 4 + 0], hs);
      hs = fmaf(xv.y, S1W[f * 4 + 1], hs);
      hs = fmaf(xv.z, S1W[f * 4 + 2], hs);
      hs = fmaf(xv.w, S1W[f * 4 + 3], hs);
      hs = fmaxf(hs, 0.0f);
      res = fmaf(hs, S2W[i * 4 + d * 2 + k], res);
    }
    out[(s0 + ss) * (NOBJ * 2) + i * 2 + d] = res;
  }
}

extern "C" void kernel_launch(void* const* d_in, const int* in_sizes, int n_in,
                              void* d_out, int out_size, void* d_ws, size_t ws_size,
                              hipStream_t stream) {
  const float* x   = (const float*)d_in[0];
  const float* L1W = (const float*)d_in[1];
  const float* L1b = (const float*)d_in[2];
  const float* L2W = (const float*)d_in[3];
  const float* L2b = (const float*)d_in[4];
  const float* I1W = (const float*)d_in[5];
  const float* I2W = (const float*)d_in[6];
  const float* I3  = (const float*)d_in[7];
  const float* S1W = (const float*)d_in[8];
  const float* S1b = (const float*)d_in[9];
  const float* S2W = (const float*)d_in[10];
  const float* S2b = (const float*)d_in[11];
  float* outp = (float*)d_out;

  magnet_fused<<<SEQ / 2, 256, 0, stream>>>(x, L1W, L1b, L2W, L2b, I1W, I2W, I3,
                                            S1W, S1b, S2W, S2b, outp);
}